// Round 1
// baseline (24691.116 us; speedup 1.0000x reference)
//
#include <hip/hip_runtime.h>
#include <hip/hip_bf16.h>

#define NS 4096
#define SEQ 2048
#define NBLK 256
#define SCAN_THREADS 256

typedef unsigned short ushort_t;

__device__ __forceinline__ float wred_sum(float v) {
#pragma unroll
  for (int o = 32; o > 0; o >>= 1) v += __shfl_xor(v, o, 64);
  return v;
}
__device__ __forceinline__ float wred_max(float v) {
#pragma unroll
  for (int o = 32; o > 0; o >>= 1) v = fmaxf(v, __shfl_xor(v, o, 64));
  return v;
}
__device__ __forceinline__ float bflo(unsigned u) { return __uint_as_float(u << 16); }
__device__ __forceinline__ float bfhi(unsigned u) { return __uint_as_float(u & 0xffff0000u); }

// ---- K1a: per-row softmax stats of T (rows r = i*2+sym, length 4096) ----
__global__ void rowstats_kernel(const float* __restrict__ T, float2* __restrict__ rstat) {
  const int r = blockIdx.x;
  const float* row = T + (size_t)r * NS;
  const int tid = threadIdx.x;
  float4 v[4];
  float mx = -1e30f;
#pragma unroll
  for (int q = 0; q < 4; ++q) {
    v[q] = *(const float4*)(row + q * 1024 + tid * 4);
    mx = fmaxf(mx, fmaxf(fmaxf(v[q].x, v[q].y), fmaxf(v[q].z, v[q].w)));
  }
  __shared__ float redm[4], reds[4];
  mx = wred_max(mx);
  if ((tid & 63) == 0) redm[tid >> 6] = mx;
  __syncthreads();
  mx = fmaxf(fmaxf(redm[0], redm[1]), fmaxf(redm[2], redm[3]));
  float se = 0.f;
#pragma unroll
  for (int q = 0; q < 4; ++q)
    se += __expf(v[q].x - mx) + __expf(v[q].y - mx) + __expf(v[q].z - mx) + __expf(v[q].w - mx);
  se = wred_sum(se);
  if ((tid & 63) == 0) reds[tid >> 6] = se;
  __syncthreads();
  if (tid == 0) {
    float tot = reds[0] + reds[1] + reds[2] + reds[3];
    rstat[r] = make_float2(mx, 1.0f / tot);
  }
}

// ---- K1b: normalize + quantize bf16 + transpose -> Tt[sym][j][i] ----
__global__ void transq_kernel(const float* __restrict__ T, const float2* __restrict__ rstat,
                              ushort_t* __restrict__ Tt) {
  const int j = blockIdx.x * 256 + threadIdx.x;
  const int i0 = blockIdx.y * 16;
  const int sym = blockIdx.z;
  ushort_t o16[16] __attribute__((aligned(16)));
#pragma unroll
  for (int ii = 0; ii < 16; ++ii) {
    const int r = (i0 + ii) * 2 + sym;
    const float2 st = rstat[r];
    const float val = T[(size_t)r * NS + j];
    const float w = __expf(val - st.x) * st.y;
    __hip_bfloat16 h = __float2bfloat16(w);
    o16[ii] = *reinterpret_cast<ushort_t*>(&h);
  }
  ushort_t* dst = Tt + ((size_t)sym * NS + j) * NS + i0;
  *(uint4*)dst = *(uint4*)(&o16[0]);
  *(uint4*)(dst + 8) = *(uint4*)(&o16[8]);
}

// ---- K2: normalize O (8192 rows of 4), keep fp32 ----
__global__ void onnorm_kernel(const float* __restrict__ O, float* __restrict__ On) {
  const int r = blockIdx.x * blockDim.x + threadIdx.x;
  if (r >= NS * 2) return;
  float4 v = *(const float4*)(O + (size_t)r * 4);
  float mx = fmaxf(fmaxf(v.x, v.y), fmaxf(v.z, v.w));
  float e0 = __expf(v.x - mx), e1 = __expf(v.y - mx), e2 = __expf(v.z - mx), e3 = __expf(v.w - mx);
  float inv = 1.0f / (e0 + e1 + e2 + e3);
  *(float4*)(On + (size_t)r * 4) = make_float4(e0 * inv, e1 * inv, e2 * inv, e3 * inv);
}

// ---- K2b: s0 = softmax(init) -> states[0] ----
__global__ void initstate_kernel(const float* __restrict__ init, float* __restrict__ s0) {
  const int tid = threadIdx.x;  // 1024 threads
  float4 v = *(const float4*)(init + tid * 4);
  float mx = fmaxf(fmaxf(v.x, v.y), fmaxf(v.z, v.w));
  __shared__ float red[16];
  mx = wred_max(mx);
  if ((tid & 63) == 0) red[tid >> 6] = mx;
  __syncthreads();
  float MX = -1e30f;
#pragma unroll
  for (int k = 0; k < 16; ++k) MX = fmaxf(MX, red[k]);
  __syncthreads();
  float e0 = __expf(v.x - MX), e1 = __expf(v.y - MX), e2 = __expf(v.z - MX), e3 = __expf(v.w - MX);
  float se = wred_sum(e0 + e1 + e2 + e3);
  if ((tid & 63) == 0) red[tid >> 6] = se;
  __syncthreads();
  float tot = 0.f;
#pragma unroll
  for (int k = 0; k < 16; ++k) tot += red[k];
  float inv = 1.0f / tot;
  *(float4*)(s0 + tid * 4) = make_float4(e0 * inv, e1 * inv, e2 * inv, e3 * inv);
}

// ---- K3: sequential scan, persistent cooperative kernel ----
// 256 blocks x 256 thr; each wave owns 4 output columns; grid barrier per step.
__global__ void __launch_bounds__(SCAN_THREADS, 1)
scan_kernel(const ushort_t* __restrict__ Tt, const int* __restrict__ seq,
            float* __restrict__ states, unsigned* __restrict__ bar) {
  __shared__ float smem[NS];
  __shared__ int sseq[SEQ];
  const int tid = threadIdx.x;
  const int lane = tid & 63;
  const int wave = tid >> 6;
  const int blk = blockIdx.x;
  const unsigned nblk = gridDim.x;

  for (int k = tid; k < SEQ; k += SCAN_THREADS) sseq[k] = seq[k];

  for (int t = 0; t < SEQ - 1; ++t) {
    const float* s = states + (size_t)t * NS;
#pragma unroll
    for (int q = 0; q < 4; ++q) {
      const int idx = (q * 256 + tid) * 4;
      *(float4*)(smem + idx) = *(const float4*)(s + idx);
    }
    __syncthreads();  // also covers sseq staging on first iteration

    float sreg[8][8];
#pragma unroll
    for (int m = 0; m < 8; ++m) {
      float4 a = *(const float4*)(smem + m * 512 + lane * 8);
      float4 b = *(const float4*)(smem + m * 512 + lane * 8 + 4);
      sreg[m][0] = a.x; sreg[m][1] = a.y; sreg[m][2] = a.z; sreg[m][3] = a.w;
      sreg[m][4] = b.x; sreg[m][5] = b.y; sreg[m][6] = b.z; sreg[m][7] = b.w;
    }

    const int sym = sseq[t];
    const int jbase = blk * 16 + wave * 4;
    const ushort_t* colbase = Tt + ((size_t)sym * NS + jbase) * NS;
    float acc[4];
#pragma unroll
    for (int c = 0; c < 4; ++c) {
      const ushort_t* col = colbase + (size_t)c * NS;
      float a = 0.f;
#pragma unroll
      for (int m = 0; m < 8; ++m) {
        const uint4 qv = *(const uint4*)(col + m * 512 + lane * 8);
        a += sreg[m][0] * bflo(qv.x);
        a += sreg[m][1] * bfhi(qv.x);
        a += sreg[m][2] * bflo(qv.y);
        a += sreg[m][3] * bfhi(qv.y);
        a += sreg[m][4] * bflo(qv.z);
        a += sreg[m][5] * bfhi(qv.z);
        a += sreg[m][6] * bflo(qv.w);
        a += sreg[m][7] * bfhi(qv.w);
      }
      acc[c] = a;
    }
#pragma unroll
    for (int c = 0; c < 4; ++c) acc[c] = wred_sum(acc[c]);
    if (lane == 0) {
      *(float4*)(states + (size_t)(t + 1) * NS + jbase) =
          make_float4(acc[0], acc[1], acc[2], acc[3]);
    }

    // grid barrier: monotonic counter. RELEASE arrival flushes dirty state
    // lines (wbl2) to L3; RELAXED spin avoids invalidating L2 (keeps T hot).
    __syncthreads();
    if (tid == 0) {
      __hip_atomic_fetch_add(bar, 1u, __ATOMIC_RELEASE, __HIP_MEMORY_SCOPE_AGENT);
      const unsigned target = (unsigned)(t + 1) * nblk;
      while (__hip_atomic_load(bar, __ATOMIC_RELAXED, __HIP_MEMORY_SCOPE_AGENT) < target) {
        __builtin_amdgcn_s_sleep(1);
      }
    }
    __syncthreads();
  }
}

// ---- K4: out[t,:] = (s_t @ On[:,y,:]) / sum(s_t)  (mass-normalized) ----
__global__ void output_kernel(const float* __restrict__ states, const float* __restrict__ On,
                              const int* __restrict__ seq, float* __restrict__ out) {
  const int t = blockIdx.x;
  const int y = seq[t];
  const float* s = states + (size_t)t * NS;
  const int tid = threadIdx.x;
  float a0 = 0, a1 = 0, a2 = 0, a3 = 0, mass = 0;
  for (int q = 0; q < 16; ++q) {
    const int i = q * 256 + tid;
    const float sv = s[i];
    const float4 on = *(const float4*)(On + ((size_t)i * 2 + y) * 4);
    a0 += sv * on.x; a1 += sv * on.y; a2 += sv * on.z; a3 += sv * on.w; mass += sv;
  }
  a0 = wred_sum(a0); a1 = wred_sum(a1); a2 = wred_sum(a2); a3 = wred_sum(a3);
  mass = wred_sum(mass);
  __shared__ float red[4][5];
  const int lane = tid & 63, wave = tid >> 6;
  if (lane == 0) { red[wave][0] = a0; red[wave][1] = a1; red[wave][2] = a2;
                   red[wave][3] = a3; red[wave][4] = mass; }
  __syncthreads();
  if (tid == 0) {
    float b0 = red[0][0] + red[1][0] + red[2][0] + red[3][0];
    float b1 = red[0][1] + red[1][1] + red[2][1] + red[3][1];
    float b2 = red[0][2] + red[1][2] + red[2][2] + red[3][2];
    float b3 = red[0][3] + red[1][3] + red[2][3] + red[3][3];
    float M  = red[0][4] + red[1][4] + red[2][4] + red[3][4];
    const float inv = 1.0f / M;
    *(float4*)(out + (size_t)t * 4) = make_float4(b0 * inv, b1 * inv, b2 * inv, b3 * inv);
  }
}

extern "C" void kernel_launch(void* const* d_in, const int* in_sizes, int n_in,
                              void* d_out, int out_size, void* d_ws, size_t ws_size,
                              hipStream_t stream) {
  const int* seq    = (const int*)d_in[0];
  const float* T    = (const float*)d_in[1];
  const float* O    = (const float*)d_in[2];
  const float* init = (const float*)d_in[3];
  float* out = (float*)d_out;

  char* ws = (char*)d_ws;
  // layout: Tt bf16 [2][4096][4096] | states f32 [2048][4096] | On f32 | rstat | bar
  ushort_t* Tt  = (ushort_t*)ws;                                   // 64 MiB
  float* states = (float*)(ws + 67108864);                         // 32 MiB
  float* On     = (float*)(ws + 67108864 + 33554432);              // 128 KiB
  float2* rstat = (float2*)(ws + 67108864 + 33554432 + 131072);    // 64 KiB
  unsigned* bar = (unsigned*)(ws + 67108864 + 33554432 + 131072 + 65536);

  hipMemsetAsync(bar, 0, 64, stream);
  hipLaunchKernelGGL(rowstats_kernel, dim3(NS * 2), dim3(256), 0, stream, T, rstat);
  hipLaunchKernelGGL(transq_kernel, dim3(16, 256, 2), dim3(256), 0, stream, T, rstat, Tt);
  hipLaunchKernelGGL(onnorm_kernel, dim3(32), dim3(256), 0, stream, O, On);
  hipLaunchKernelGGL(initstate_kernel, dim3(1), dim3(1024), 0, stream, init, states);

  void* kargs[] = { (void*)&Tt, (void*)&seq, (void*)&states, (void*)&bar };
  hipLaunchCooperativeKernel((void*)scan_kernel, dim3(NBLK), dim3(SCAN_THREADS),
                             kargs, 0, stream);

  hipLaunchKernelGGL(output_kernel, dim3(SEQ), dim3(256), 0, stream, states, On, seq, out);
}